// Round 2
// baseline (640.431 us; speedup 1.0000x reference)
//
#include <hip/hip_runtime.h>
#include <hip/hip_bf16.h>

// Problem constants (B=256, T=512, D=512, H=64)
#define BB 256
#define TT 512
#define DD 512
#define HH 64
#define NG 256            // 4*H gates
#define MM (BB * TT)      // 131072 rows of x_proj

// GEMM tiling
#define BM 128
#define BN 256
#define BK 32
#define LDA 40            // padded LDS row stride (80B rows: 8B-aligned b64 ops, 2-way banks = free)
#define LDB 40
#define NKC (DD / BK)     // 16 K-chunks

typedef short short8 __attribute__((ext_vector_type(8)));
typedef short short4v __attribute__((ext_vector_type(4)));
typedef float f32x4 __attribute__((ext_vector_type(4)));

// fp32x4 -> packed 4x bf16 (RNE) as a 64-bit value
__device__ inline unsigned long long pack4bf16(float4 v) {
    __hip_bfloat162 lo = __float22bfloat162_rn(make_float2(v.x, v.y));
    __hip_bfloat162 hi = __float22bfloat162_rn(make_float2(v.z, v.w));
    unsigned lu, hu;
    __builtin_memcpy(&lu, &lo, 4);
    __builtin_memcpy(&hu, &hi, 4);
    return ((unsigned long long)hu << 32) | lu;
}

__device__ inline unsigned short f2bf(float f) {
    __hip_bfloat16 h = __float2bfloat16(f);   // RNE
    unsigned short u;
    __builtin_memcpy(&u, &h, 2);
    return u;
}

__device__ inline float bf2f(unsigned short u) {
    unsigned x = ((unsigned)u) << 16;
    float f;
    __builtin_memcpy(&f, &x, 4);
    return f;
}

// ---------------------------------------------------------------------------
// Phase 1: XP[m,g] = X[m,:] . W_ih[g,:] + (b_ih[g]+b_hh[g]),  stored as BF16.
// bf16 MFMA GEMM. 512 threads = 8 waves in 2x4; per-wave C = 64x64.
// Double-buffered LDS, ONE barrier per K-iter; next tile's global loads
// issued a full iteration before their LDS-stage.
// ---------------------------------------------------------------------------
__global__ __launch_bounds__(512, 2) void gemm_xproj(
    const float* __restrict__ X,     // [MM, DD]
    const float* __restrict__ W,     // [NG, DD]
    const float* __restrict__ b_ih,  // [NG]
    const float* __restrict__ b_hh,  // [NG]
    unsigned short* __restrict__ XP) // [MM, NG] bf16
{
    __shared__ unsigned short As[2][BM * LDA];   // 2 x 10240 B
    __shared__ unsigned short Bs[2][BN * LDB];   // 2 x 20480 B
    __shared__ float bias_s[NG];

    const int tid   = threadIdx.x;
    const int m_blk = blockIdx.x * BM;
    const int lane  = tid & 63;
    const int wv    = tid >> 6;      // wave 0..7
    const int wm    = wv & 1;        // M half (64 rows)
    const int wn    = wv >> 1;       // N quarter (64 cols)
    const int q     = lane >> 4;     // k-quad
    const int cn    = lane & 15;

    if (tid < NG) bias_s[tid] = b_ih[tid] + b_hh[tid];

    f32x4 acc[4][4];
#pragma unroll
    for (int i = 0; i < 4; ++i)
#pragma unroll
        for (int j = 0; j < 4; ++j) acc[i][j] = (f32x4)0.f;

    float4 a_r[2], b_r[4];

    // tile-k loads: A 128x32 fp32 = 1024 float4 (2/thread), B 256x32 = 2048 (4/thread)
#define LOAD_TILE(KC)                                                                     \
    do {                                                                                  \
        const int kof = (KC) * BK;                                                        \
        _Pragma("unroll")                                                                 \
        for (int u = 0; u < 2; ++u) {                                                     \
            int c = tid + 512 * u;                                                        \
            a_r[u] = *(const float4*)(X + (size_t)(m_blk + (c >> 3)) * DD + kof + (c & 7) * 4); \
        }                                                                                 \
        _Pragma("unroll")                                                                 \
        for (int u = 0; u < 4; ++u) {                                                     \
            int c = tid + 512 * u;                                                        \
            b_r[u] = *(const float4*)(W + (size_t)(c >> 3) * DD + kof + (c & 7) * 4);     \
        }                                                                                 \
    } while (0)

    LOAD_TILE(0);

    for (int kc = 0; kc < NKC; ++kc) {
        const int p = kc & 1;
        // stage current regs -> LDS[p] (bf16)
#pragma unroll
        for (int u = 0; u < 2; ++u) {
            int c = tid + 512 * u;
            *(unsigned long long*)&As[p][(c >> 3) * LDA + (c & 7) * 4] = pack4bf16(a_r[u]);
        }
#pragma unroll
        for (int u = 0; u < 4; ++u) {
            int c = tid + 512 * u;
            *(unsigned long long*)&Bs[p][(c >> 3) * LDB + (c & 7) * 4] = pack4bf16(b_r[u]);
        }
        // prefetch next tile (consumed next iteration, after the next barrier)
        if (kc + 1 < NKC) LOAD_TILE(kc + 1);
        __syncthreads();

        // LDS -> fragments (two b64 reads each: 80B rows are 8B-aligned)
        short8 af[4], bf[4];
#pragma unroll
        for (int i = 0; i < 4; ++i) {
            const unsigned short* pa = &As[p][(wm * 64 + i * 16 + cn) * LDA + q * 8];
            ((short4v*)&af[i])[0] = *(const short4v*)pa;
            ((short4v*)&af[i])[1] = *(const short4v*)(pa + 4);
        }
#pragma unroll
        for (int j = 0; j < 4; ++j) {
            const unsigned short* pb = &Bs[p][(wn * 64 + j * 16 + cn) * LDB + q * 8];
            ((short4v*)&bf[j])[0] = *(const short4v*)pb;
            ((short4v*)&bf[j])[1] = *(const short4v*)(pb + 4);
        }

#pragma unroll
        for (int i = 0; i < 4; ++i)
#pragma unroll
            for (int j = 0; j < 4; ++j)
                acc[i][j] = __builtin_amdgcn_mfma_f32_16x16x32_bf16(af[i], bf[j], acc[i][j], 0, 0, 0);
    }

    // epilogue: C/D layout col = lane&15 (n), row = quad*4 + reg (m); bf16 store
#pragma unroll
    for (int j = 0; j < 4; ++j) {
        const int n   = wn * 64 + j * 16 + cn;
        const float bvv = bias_s[n];
#pragma unroll
        for (int i = 0; i < 4; ++i) {
            const int m0 = m_blk + wm * 64 + i * 16 + q * 4;
#pragma unroll
            for (int r = 0; r < 4; ++r)
                XP[(size_t)(m0 + r) * NG + n] = f2bf(acc[i][j][r] + bvv);
        }
    }
#undef LOAD_TILE
}

// ---------------------------------------------------------------------------
// Phase 2: LSTM recurrence. 1 batch/block, thread = gate, wave = gate type.
// h replicated per wave (lane j holds h_j); matvec = readlane broadcast into
// FOUR independent FMA chains. Gate exchange via double-buffered LDS, one
// barrier per step. XP is bf16 (converted at use); recurrence math all fp32.
//
// __launch_bounds__(256, 1): B=256 gives exactly 1 block/CU (4 waves, 1/SIMD),
// so occupancy is structurally capped — do NOT let the backend target 8
// waves/EU (that capped VGPRs at 64 and spilled wrow[64] to scratch:
// VGPR_Count=44 + 64 scratch loads per step was the R1 stall).
// ---------------------------------------------------------------------------
__global__ __launch_bounds__(256, 1) void lstm_rec(
    const unsigned short* __restrict__ XP,  // [BB, TT, NG] bf16
    const float* __restrict__ Whh,          // [NG, HH]
    float* __restrict__ pooled)             // [BB, HH]
{
    const int b   = blockIdx.x;
    const int tid = threadIdx.x;
    const int wv  = tid >> 6;
    const int j   = tid & 63;

    float wrow[HH];
#pragma unroll
    for (int u = 0; u < HH / 4; ++u)
        ((float4*)wrow)[u] = ((const float4*)(Whh + (size_t)tid * HH))[u];

    __shared__ float gbuf[2][NG];

    float h = 0.f, c = 0.f, hsum = 0.f;
    const unsigned short* xp = XP + (size_t)b * TT * NG + tid;

    // prefetch ring depth 4; wraps at the end (dead loads, valid addresses)
    unsigned short xr[4];
#pragma unroll
    for (int u = 0; u < 4; ++u) xr[u] = xp[(size_t)u * NG];

    for (int t0 = 0; t0 < TT; t0 += 4) {
#pragma unroll
        for (int u = 0; u < 4; ++u) {
            const int t = t0 + u;
            float a0 = bf2f(xr[u]), a1 = 0.f, a2 = 0.f, a3 = 0.f;
            xr[u] = xp[(size_t)((t + 4) & (TT - 1)) * NG];

            const int hb = __float_as_int(h);
#pragma unroll
            for (int kb = 0; kb < HH; kb += 4) {
                float h0 = __int_as_float(__builtin_amdgcn_readlane(hb, kb + 0));
                float h1 = __int_as_float(__builtin_amdgcn_readlane(hb, kb + 1));
                float h2 = __int_as_float(__builtin_amdgcn_readlane(hb, kb + 2));
                float h3 = __int_as_float(__builtin_amdgcn_readlane(hb, kb + 3));
                a0 = fmaf(wrow[kb + 0], h0, a0);
                a1 = fmaf(wrow[kb + 1], h1, a1);
                a2 = fmaf(wrow[kb + 2], h2, a2);
                a3 = fmaf(wrow[kb + 3], h3, a3);
            }
            const float acc = (a0 + a1) + (a2 + a3);

            float a;
            if (wv == 2) {                          // tanh gate (wave-uniform)
                a = 2.f / (1.f + __expf(-2.f * acc)) - 1.f;
            } else {                                // sigmoid gates
                a = 1.f / (1.f + __expf(-acc));
            }
            const int p = t & 1;
            gbuf[p][tid] = a;
            __syncthreads();
            const float iv = gbuf[p][j];
            const float fv = gbuf[p][64 + j];
            const float gv = gbuf[p][128 + j];
            const float ov = gbuf[p][192 + j];
            c = fmaf(fv, c, iv * gv);
            const float th = 2.f / (1.f + __expf(-2.f * c)) - 1.f;
            h = ov * th;
            hsum += h;
        }
    }

    if (tid < HH) pooled[(size_t)b * HH + j] = hsum * (1.f / (float)TT);
}

// ---------------------------------------------------------------------------
// Phase 3: MLP head + softmax. One block, one thread per batch row.
// ---------------------------------------------------------------------------
__global__ __launch_bounds__(256) void head_kernel(
    const float* __restrict__ pooled,  // [BB, HH]
    const float* __restrict__ W1,      // [32, HH]
    const float* __restrict__ b1,      // [32]
    const float* __restrict__ W2,      // [3, 32]
    const float* __restrict__ b2,      // [3]
    float* __restrict__ out)           // [BB, 3]
{
    __shared__ float W1s[32 * HH];
    __shared__ float W2s[3 * 32];
    __shared__ float b1s[32];
    __shared__ float b2s[3];

    const int tid = threadIdx.x;
    for (int i = tid; i < 32 * HH; i += 256) W1s[i] = W1[i];
    if (tid < 96) W2s[tid] = W2[tid];
    if (tid < 32) b1s[tid] = b1[tid];
    if (tid < 3)  b2s[tid] = b2[tid];
    __syncthreads();

    float p[HH];
    const float4* p4 = (const float4*)(pooled + (size_t)tid * HH);
#pragma unroll
    for (int q = 0; q < HH / 4; ++q) ((float4*)p)[q] = p4[q];

    float hbuf[32];
#pragma unroll
    for (int k = 0; k < 32; ++k) {
        float s = b1s[k];
        const float* wr = &W1s[k * HH];
#pragma unroll
        for (int jj = 0; jj < HH; ++jj) s += p[jj] * wr[jj];
        hbuf[k] = s > 0.f ? s : 0.f;
    }

    float lg[3];
#pragma unroll
    for (int cc = 0; cc < 3; ++cc) {
        float s = b2s[cc];
        const float* wr = &W2s[cc * 32];
#pragma unroll
        for (int k = 0; k < 32; ++k) s += hbuf[k] * wr[k];
        lg[cc] = s;
    }

    float mx = fmaxf(lg[0], fmaxf(lg[1], lg[2]));
    float e0 = __expf(lg[0] - mx);
    float e1 = __expf(lg[1] - mx);
    float e2 = __expf(lg[2] - mx);
    float inv = 1.f / (e0 + e1 + e2);
    out[tid * 3 + 0] = e0 * inv;
    out[tid * 3 + 1] = e1 * inv;
    out[tid * 3 + 2] = e2 * inv;
}

// ---------------------------------------------------------------------------
extern "C" void kernel_launch(void* const* d_in, const int* in_sizes, int n_in,
                              void* d_out, int out_size, void* d_ws, size_t ws_size,
                              hipStream_t stream) {
    const float* x    = (const float*)d_in[0];  // [256,512,512]
    const float* W_ih = (const float*)d_in[1];  // [256,512]
    const float* W_hh = (const float*)d_in[2];  // [256,64]
    const float* b_ih = (const float*)d_in[3];  // [256]
    const float* b_hh = (const float*)d_in[4];  // [256]
    const float* W1   = (const float*)d_in[5];  // [32,64]
    const float* b1   = (const float*)d_in[6];  // [32]
    const float* W2   = (const float*)d_in[7];  // [3,32]
    const float* b2   = (const float*)d_in[8];  // [3]
    float* out = (float*)d_out;

    // workspace layout: XP [MM*NG] bf16 (64 MiB), then pooled [BB*HH] fp32
    unsigned short* XP = (unsigned short*)d_ws;
    float* pooled = (float*)((char*)d_ws + (size_t)MM * NG * sizeof(unsigned short));

    gemm_xproj<<<dim3(MM / BM), 512, 0, stream>>>(x, W_ih, b_ih, b_hh, XP);
    lstm_rec<<<dim3(BB), 256, 0, stream>>>(XP, W_hh, pooled);
    head_kernel<<<dim3(1), 256, 0, stream>>>(pooled, W1, b1, W2, b2, out);
}

// Round 3
// 631.904 us; speedup vs baseline: 1.0135x; 1.0135x over previous
//
#include <hip/hip_runtime.h>
#include <hip/hip_bf16.h>

// Problem constants (B=256, T=512, D=512, H=64)
#define BB 256
#define TT 512
#define DD 512
#define HH 64
#define NG 256            // 4*H gates
#define MM (BB * TT)      // 131072 rows of x_proj

// GEMM tiling
#define BM 128
#define BN 256
#define BK 32
#define LDA 40            // padded LDS row stride (80B rows: 8B-aligned b64 ops, 2-way banks = free)
#define LDB 40
#define NKC (DD / BK)     // 16 K-chunks

typedef short short8 __attribute__((ext_vector_type(8)));
typedef short short4v __attribute__((ext_vector_type(4)));
typedef float f32x4 __attribute__((ext_vector_type(4)));

// fp32x4 -> packed 4x bf16 (RNE) as a 64-bit value
__device__ inline unsigned long long pack4bf16(float4 v) {
    __hip_bfloat162 lo = __float22bfloat162_rn(make_float2(v.x, v.y));
    __hip_bfloat162 hi = __float22bfloat162_rn(make_float2(v.z, v.w));
    unsigned lu, hu;
    __builtin_memcpy(&lu, &lo, 4);
    __builtin_memcpy(&hu, &hi, 4);
    return ((unsigned long long)hu << 32) | lu;
}

__device__ inline unsigned short f2bf(float f) {
    __hip_bfloat16 h = __float2bfloat16(f);   // RNE
    unsigned short u;
    __builtin_memcpy(&u, &h, 2);
    return u;
}

__device__ inline float bf2f(unsigned short u) {
    unsigned x = ((unsigned)u) << 16;
    float f;
    __builtin_memcpy(&f, &x, 4);
    return f;
}

// ---------------------------------------------------------------------------
// Phase 1: XP[m,g] = X[m,:] . W_ih[g,:] + (b_ih[g]+b_hh[g]),  stored as BF16.
// bf16 MFMA GEMM. 512 threads = 8 waves in 2x4; per-wave C = 64x64.
// Double-buffered LDS, ONE barrier per K-iter; next tile's global loads
// issued a full iteration before their LDS-stage.
// ---------------------------------------------------------------------------
__global__ __launch_bounds__(512, 2) void gemm_xproj(
    const float* __restrict__ X,     // [MM, DD]
    const float* __restrict__ W,     // [NG, DD]
    const float* __restrict__ b_ih,  // [NG]
    const float* __restrict__ b_hh,  // [NG]
    unsigned short* __restrict__ XP) // [MM, NG] bf16
{
    __shared__ unsigned short As[2][BM * LDA];   // 2 x 10240 B
    __shared__ unsigned short Bs[2][BN * LDB];   // 2 x 20480 B
    __shared__ float bias_s[NG];

    const int tid   = threadIdx.x;
    const int m_blk = blockIdx.x * BM;
    const int lane  = tid & 63;
    const int wv    = tid >> 6;      // wave 0..7
    const int wm    = wv & 1;        // M half (64 rows)
    const int wn    = wv >> 1;       // N quarter (64 cols)
    const int q     = lane >> 4;     // k-quad
    const int cn    = lane & 15;

    if (tid < NG) bias_s[tid] = b_ih[tid] + b_hh[tid];

    f32x4 acc[4][4];
#pragma unroll
    for (int i = 0; i < 4; ++i)
#pragma unroll
        for (int j = 0; j < 4; ++j) acc[i][j] = (f32x4)0.f;

    float4 a_r[2], b_r[4];

    // tile-k loads: A 128x32 fp32 = 1024 float4 (2/thread), B 256x32 = 2048 (4/thread)
#define LOAD_TILE(KC)                                                                     \
    do {                                                                                  \
        const int kof = (KC) * BK;                                                        \
        _Pragma("unroll")                                                                 \
        for (int u = 0; u < 2; ++u) {                                                     \
            int c = tid + 512 * u;                                                        \
            a_r[u] = *(const float4*)(X + (size_t)(m_blk + (c >> 3)) * DD + kof + (c & 7) * 4); \
        }                                                                                 \
        _Pragma("unroll")                                                                 \
        for (int u = 0; u < 4; ++u) {                                                     \
            int c = tid + 512 * u;                                                        \
            b_r[u] = *(const float4*)(W + (size_t)(c >> 3) * DD + kof + (c & 7) * 4);     \
        }                                                                                 \
    } while (0)

    LOAD_TILE(0);

    for (int kc = 0; kc < NKC; ++kc) {
        const int p = kc & 1;
        // stage current regs -> LDS[p] (bf16)
#pragma unroll
        for (int u = 0; u < 2; ++u) {
            int c = tid + 512 * u;
            *(unsigned long long*)&As[p][(c >> 3) * LDA + (c & 7) * 4] = pack4bf16(a_r[u]);
        }
#pragma unroll
        for (int u = 0; u < 4; ++u) {
            int c = tid + 512 * u;
            *(unsigned long long*)&Bs[p][(c >> 3) * LDB + (c & 7) * 4] = pack4bf16(b_r[u]);
        }
        // prefetch next tile (consumed next iteration, after the next barrier)
        if (kc + 1 < NKC) LOAD_TILE(kc + 1);
        __syncthreads();

        // LDS -> fragments (two b64 reads each: 80B rows are 8B-aligned)
        short8 af[4], bf[4];
#pragma unroll
        for (int i = 0; i < 4; ++i) {
            const unsigned short* pa = &As[p][(wm * 64 + i * 16 + cn) * LDA + q * 8];
            ((short4v*)&af[i])[0] = *(const short4v*)pa;
            ((short4v*)&af[i])[1] = *(const short4v*)(pa + 4);
        }
#pragma unroll
        for (int j = 0; j < 4; ++j) {
            const unsigned short* pb = &Bs[p][(wn * 64 + j * 16 + cn) * LDB + q * 8];
            ((short4v*)&bf[j])[0] = *(const short4v*)pb;
            ((short4v*)&bf[j])[1] = *(const short4v*)(pb + 4);
        }

#pragma unroll
        for (int i = 0; i < 4; ++i)
#pragma unroll
            for (int j = 0; j < 4; ++j)
                acc[i][j] = __builtin_amdgcn_mfma_f32_16x16x32_bf16(af[i], bf[j], acc[i][j], 0, 0, 0);
    }

    // epilogue: C/D layout col = lane&15 (n), row = quad*4 + reg (m); bf16 store
#pragma unroll
    for (int j = 0; j < 4; ++j) {
        const int n   = wn * 64 + j * 16 + cn;
        const float bvv = bias_s[n];
#pragma unroll
        for (int i = 0; i < 4; ++i) {
            const int m0 = m_blk + wm * 64 + i * 16 + q * 4;
#pragma unroll
            for (int r = 0; r < 4; ++r)
                XP[(size_t)(m0 + r) * NG + n] = f2bf(acc[i][j][r] + bvv);
        }
    }
#undef LOAD_TILE
}

// ---------------------------------------------------------------------------
// Phase 2: LSTM recurrence. 1 batch/block, thread = gate, wave = gate type.
// h replicated per wave (lane j holds h_j); matvec = readlane broadcast into
// FOUR independent FMA chains. Gate exchange via double-buffered LDS, one
// barrier per step. XP is bf16 (converted at use); recurrence math all fp32.
//
// W_hh row is held in SIXTEEN NAMED f32x4 VARIABLES with macro-expanded MAC
// blocks: R1/R2 showed VGPR_Count=44 (< 64 floats of the row!) — the kb-loop
// was not fully unrolled, so wrow[kb] was runtime-indexed -> scratch, and
// every step re-loaded 64 W values via buffer-loads (rule #20). Named vars
// make register residency non-negotiable.
// ---------------------------------------------------------------------------
__global__ __launch_bounds__(256, 1) void lstm_rec(
    const unsigned short* __restrict__ XP,  // [BB, TT, NG] bf16
    const float* __restrict__ Whh,          // [NG, HH]
    float* __restrict__ pooled)             // [BB, HH]
{
    const int b   = blockIdx.x;
    const int tid = threadIdx.x;
    const int wv  = tid >> 6;
    const int j   = tid & 63;

    const f32x4* Wv = (const f32x4*)(Whh + (size_t)tid * HH);
#define WLOAD(i) const f32x4 w##i = Wv[i];
    WLOAD(0)  WLOAD(1)  WLOAD(2)  WLOAD(3)
    WLOAD(4)  WLOAD(5)  WLOAD(6)  WLOAD(7)
    WLOAD(8)  WLOAD(9)  WLOAD(10) WLOAD(11)
    WLOAD(12) WLOAD(13) WLOAD(14) WLOAD(15)
#undef WLOAD

    __shared__ float gbuf[2][NG];

    float h = 0.f, c = 0.f, hsum = 0.f;
    const unsigned short* xp = XP + (size_t)b * TT * NG + tid;

    // prefetch ring depth 4; wraps at the end (dead loads, valid addresses)
    unsigned short xr0 = xp[0];
    unsigned short xr1 = xp[(size_t)1 * NG];
    unsigned short xr2 = xp[(size_t)2 * NG];
    unsigned short xr3 = xp[(size_t)3 * NG];

    // one 4-wide MAC block: broadcast h[K..K+3] via readlane, FMA into 4 chains
#define MAC4(W, K)                                                        \
    {                                                                     \
        float h0 = __int_as_float(__builtin_amdgcn_readlane(hb, (K)+0));  \
        float h1 = __int_as_float(__builtin_amdgcn_readlane(hb, (K)+1));  \
        float h2 = __int_as_float(__builtin_amdgcn_readlane(hb, (K)+2));  \
        float h3 = __int_as_float(__builtin_amdgcn_readlane(hb, (K)+3));  \
        a0 = fmaf(W[0], h0, a0);                                          \
        a1 = fmaf(W[1], h1, a1);                                          \
        a2 = fmaf(W[2], h2, a2);                                          \
        a3 = fmaf(W[3], h3, a3);                                          \
    }

#define LSTM_STEP(T_, XRCUR)                                              \
    {                                                                     \
        const int t = (T_);                                               \
        float a0 = bf2f(XRCUR), a1 = 0.f, a2 = 0.f, a3 = 0.f;             \
        XRCUR = xp[(size_t)((t + 4) & (TT - 1)) * NG];                    \
        const int hb = __float_as_int(h);                                 \
        MAC4(w0,  0)  MAC4(w1,  4)  MAC4(w2,  8)  MAC4(w3,  12)           \
        MAC4(w4,  16) MAC4(w5,  20) MAC4(w6,  24) MAC4(w7,  28)           \
        MAC4(w8,  32) MAC4(w9,  36) MAC4(w10, 40) MAC4(w11, 44)           \
        MAC4(w12, 48) MAC4(w13, 52) MAC4(w14, 56) MAC4(w15, 60)           \
        const float acc = (a0 + a1) + (a2 + a3);                          \
        float a;                                                          \
        if (wv == 2) {                                                    \
            a = 2.f / (1.f + __expf(-2.f * acc)) - 1.f;                   \
        } else {                                                          \
            a = 1.f / (1.f + __expf(-acc));                               \
        }                                                                 \
        const int p = t & 1;                                              \
        gbuf[p][tid] = a;                                                 \
        __syncthreads();                                                  \
        const float iv = gbuf[p][j];                                      \
        const float fv = gbuf[p][64 + j];                                 \
        const float gv = gbuf[p][128 + j];                                \
        const float ov = gbuf[p][192 + j];                                \
        c = fmaf(fv, c, iv * gv);                                         \
        const float th = 2.f / (1.f + __expf(-2.f * c)) - 1.f;            \
        h = ov * th;                                                      \
        hsum += h;                                                        \
    }

    for (int t0 = 0; t0 < TT; t0 += 4) {
        LSTM_STEP(t0 + 0, xr0)
        LSTM_STEP(t0 + 1, xr1)
        LSTM_STEP(t0 + 2, xr2)
        LSTM_STEP(t0 + 3, xr3)
    }
#undef LSTM_STEP
#undef MAC4

    if (tid < HH) pooled[(size_t)b * HH + j] = hsum * (1.f / (float)TT);
}

// ---------------------------------------------------------------------------
// Phase 3: MLP head + softmax. One block, one thread per batch row.
// ---------------------------------------------------------------------------
__global__ __launch_bounds__(256) void head_kernel(
    const float* __restrict__ pooled,  // [BB, HH]
    const float* __restrict__ W1,      // [32, HH]
    const float* __restrict__ b1,      // [32]
    const float* __restrict__ W2,      // [3, 32]
    const float* __restrict__ b2,      // [3]
    float* __restrict__ out)           // [BB, 3]
{
    __shared__ float W1s[32 * HH];
    __shared__ float W2s[3 * 32];
    __shared__ float b1s[32];
    __shared__ float b2s[3];

    const int tid = threadIdx.x;
    for (int i = tid; i < 32 * HH; i += 256) W1s[i] = W1[i];
    if (tid < 96) W2s[tid] = W2[tid];
    if (tid < 32) b1s[tid] = b1[tid];
    if (tid < 3)  b2s[tid] = b2[tid];
    __syncthreads();

    float p[HH];
    const float4* p4 = (const float4*)(pooled + (size_t)tid * HH);
#pragma unroll
    for (int q = 0; q < HH / 4; ++q) ((float4*)p)[q] = p4[q];

    float hbuf[32];
#pragma unroll
    for (int k = 0; k < 32; ++k) {
        float s = b1s[k];
        const float* wr = &W1s[k * HH];
#pragma unroll
        for (int jj = 0; jj < HH; ++jj) s += p[jj] * wr[jj];
        hbuf[k] = s > 0.f ? s : 0.f;
    }

    float lg[3];
#pragma unroll
    for (int cc = 0; cc < 3; ++cc) {
        float s = b2s[cc];
        const float* wr = &W2s[cc * 32];
#pragma unroll
        for (int k = 0; k < 32; ++k) s += hbuf[k] * wr[k];
        lg[cc] = s;
    }

    float mx = fmaxf(lg[0], fmaxf(lg[1], lg[2]));
    float e0 = __expf(lg[0] - mx);
    float e1 = __expf(lg[1] - mx);
    float e2 = __expf(lg[2] - mx);
    float inv = 1.f / (e0 + e1 + e2);
    out[tid * 3 + 0] = e0 * inv;
    out[tid * 3 + 1] = e1 * inv;
    out[tid * 3 + 2] = e2 * inv;
}

// ---------------------------------------------------------------------------
extern "C" void kernel_launch(void* const* d_in, const int* in_sizes, int n_in,
                              void* d_out, int out_size, void* d_ws, size_t ws_size,
                              hipStream_t stream) {
    const float* x    = (const float*)d_in[0];  // [256,512,512]
    const float* W_ih = (const float*)d_in[1];  // [256,512]
    const float* W_hh = (const float*)d_in[2];  // [256,64]
    const float* b_ih = (const float*)d_in[3];  // [256]
    const float* b_hh = (const float*)d_in[4];  // [256]
    const float* W1   = (const float*)d_in[5];  // [32,64]
    const float* b1   = (const float*)d_in[6];  // [32]
    const float* W2   = (const float*)d_in[7];  // [3,32]
    const float* b2   = (const float*)d_in[8];  // [3]
    float* out = (float*)d_out;

    // workspace layout: XP [MM*NG] bf16 (64 MiB), then pooled [BB*HH] fp32
    unsigned short* XP = (unsigned short*)d_ws;
    float* pooled = (float*)((char*)d_ws + (size_t)MM * NG * sizeof(unsigned short));

    gemm_xproj<<<dim3(MM / BM), 512, 0, stream>>>(x, W_ih, b_ih, b_hh, XP);
    lstm_rec<<<dim3(BB), 256, 0, stream>>>(XP, W_hh, pooled);
    head_kernel<<<dim3(1), 256, 0, stream>>>(pooled, W1, b1, W2, b2, out);
}